// Round 8
// baseline (597.029 us; speedup 1.0000x reference)
//
#include <hip/hip_runtime.h>

#define NN 50000
#define EE 800000
#define BB 1000
#define NB 196  // ceil(NN/256)
#define NR 8        // node ranges for LDS histogram
#define RS 6272     // range size, NR*RS = 50176 >= NN
#define NC 32       // edge chunks / partial copies
#define CHUNK 25000 // EE/NC

// two-pass scatter: 160 dst ranges of 314 rows; bin -> in-LDS sort
#define NRB 160
#define RSB 314     // 160*314 = 50240 >= NN
#define NBIN 256    // bin blocks
#define CH2 3125    // EE/NBIN
#define CAP 7000    // per-range LDS image capacity (mean 5024, +28 sigma)

typedef unsigned short u16;
typedef unsigned long long u64;
typedef __attribute__((ext_vector_type(8))) short bf16x8;
typedef __attribute__((ext_vector_type(4))) short bf16x4;
typedef __attribute__((ext_vector_type(4))) float f32x4;

static __device__ __forceinline__ u16 f2b(float f) {
    union { float f; unsigned u; } v;
    v.f = f;
    unsigned r = v.u + 0x7fffu + ((v.u >> 16) & 1u);
    return (u16)(r >> 16);
}

static __device__ __forceinline__ float b2f(short s) {
    union { unsigned u; float f; } c;
    c.u = ((unsigned)(u16)s) << 16;
    return c.f;
}

// ---------------- degree(src)+indegree(dst): LDS-privatized, zero global atomics ----------------
__global__ __launch_bounds__(512) void k_degcnt_lds(
    const int* __restrict__ src, const int* __restrict__ dst,
    const float* __restrict__ ew, float* __restrict__ deg_p,
    int* __restrict__ cnt_p) {
    __shared__ float sdeg[RS];
    __shared__ int scnt[RS];
    int r = blockIdx.x & (NR - 1);
    int c = blockIdx.x >> 3;
    int base = r * RS;
    for (int i = threadIdx.x; i < RS; i += 512) {
        sdeg[i] = 0.f;
        scnt[i] = 0;
    }
    __syncthreads();
    int e0 = c * CHUNK;
    for (int j = threadIdx.x; j < CHUNK; j += 512) {
        int e = e0 + j;
        int s = src[e], d = dst[e];
        int sl = s - base, dl = d - base;
        if ((unsigned)sl < RS) atomicAdd(&sdeg[sl], ew[e]);
        if ((unsigned)dl < RS) atomicAdd(&scnt[dl], 1);
    }
    __syncthreads();
    int lim = (NN - base < RS) ? (NN - base) : RS;
    for (int i = threadIdx.x; i < lim; i += 512) {
        deg_p[(size_t)c * NN + base + i] = sdeg[i];
        cnt_p[(size_t)c * NN + base + i] = scnt[i];
    }
}

// ---------------- CSR scan ----------------
__global__ void k_scan1(const int* __restrict__ cnt_p, int* __restrict__ cnt,
                        int* __restrict__ incl, int* __restrict__ bsum) {
    __shared__ int s[256];
    int i = blockIdx.x * 256 + threadIdx.x;
    int v = 0;
    if (i < NN) {
#pragma unroll
        for (int p = 0; p < NC; p++) v += cnt_p[(size_t)p * NN + i];
        cnt[i] = v;
    }
    s[threadIdx.x] = v;
    __syncthreads();
    for (int off = 1; off < 256; off <<= 1) {
        int t = (threadIdx.x >= off) ? s[threadIdx.x - off] : 0;
        __syncthreads();
        s[threadIdx.x] += t;
        __syncthreads();
    }
    if (i < NN) incl[i] = s[threadIdx.x];
    if (threadIdx.x == 255) bsum[blockIdx.x] = s[255];
}

__global__ void k_scan2(int* __restrict__ bsum) {
    __shared__ int s[256];
    int v = (threadIdx.x < NB) ? bsum[threadIdx.x] : 0;
    s[threadIdx.x] = v;
    __syncthreads();
    for (int off = 1; off < 256; off <<= 1) {
        int t = (threadIdx.x >= off) ? s[threadIdx.x - off] : 0;
        __syncthreads();
        s[threadIdx.x] += t;
        __syncthreads();
    }
    if (threadIdx.x < NB) bsum[threadIdx.x] = s[threadIdx.x];
}

__global__ void k_scan3(const int* __restrict__ incl, const int* __restrict__ cnt,
                        const int* __restrict__ bsum, int* __restrict__ row_ptr,
                        int* __restrict__ scur, const float* __restrict__ deg_p,
                        float* __restrict__ dinv) {
    int i = blockIdx.x * 256 + threadIdx.x;
    if (i >= NN) return;
    int off = (blockIdx.x > 0) ? bsum[blockIdx.x - 1] : 0;
    int start = off + incl[i] - cnt[i];
    row_ptr[i] = start;
    if (i % RSB == 0) scur[i / RSB] = start;
    float d = 0.f;
#pragma unroll
    for (int p = 0; p < NC; p++) d += deg_p[(size_t)p * NN + i];
    dinv[i] = d > 0.f ? rsqrtf(d) : 0.f;
}

// ---------------- pass B: bin edges by dst range, append packed records ----------------
__global__ __launch_bounds__(512) void k_bin(
    const int* __restrict__ src, const int* __restrict__ dst,
    const float* __restrict__ ew, const float* __restrict__ dinv,
    int* __restrict__ scur, u64* __restrict__ stage) {
    __shared__ int cntA[NRB], baseB[NRB], rk[NRB];
    int e0 = blockIdx.x * CH2;
    for (int i = threadIdx.x; i < NRB; i += 512) cntA[i] = 0;
    __syncthreads();
    for (int j = threadIdx.x; j < CH2; j += 512) {
        int d = dst[e0 + j];
        atomicAdd(&cntA[d / RSB], 1);
    }
    __syncthreads();
    for (int i = threadIdx.x; i < NRB; i += 512) {
        baseB[i] = atomicAdd(&scur[i], cntA[i]);
        rk[i] = 0;
    }
    __syncthreads();
    for (int j = threadIdx.x; j < CH2; j += 512) {
        int e = e0 + j;
        int d = dst[e], s = src[e];
        int r = d / RSB;
        int slot = baseB[r] + atomicAdd(&rk[r], 1);
        float w = dinv[s] * ew[e] * dinv[d];
        unsigned dl = (unsigned)(d - r * RSB);
        u64 rec = ((u64)((dl << 16) | (unsigned)s) << 32) | (u64)__float_as_uint(w);
        stage[slot] = rec;
    }
}

// ---------------- pass C: per-range in-LDS counting sort -> coalesced CSR write ----------------
__global__ __launch_bounds__(512) void k_sortrange(
    const u64* __restrict__ stage, const int* __restrict__ row_ptr,
    uint2* __restrict__ csr8) {
    __shared__ uint2 img[CAP];
    __shared__ int cur[RSB];
    int r = blockIdx.x;
    int r0 = r * RSB;
    int nrows = (NN - r0 < RSB) ? (NN - r0) : RSB;
    int p0 = row_ptr[r0];
    int p1 = (r0 + nrows < NN) ? row_ptr[r0 + nrows] : EE;
    for (int i = threadIdx.x; i < nrows; i += 512) cur[i] = row_ptr[r0 + i] - p0;
    __syncthreads();
    int n = p1 - p0;
    for (int j = threadIdx.x; j < n; j += 512) {
        u64 rec = stage[p0 + j];
        unsigned hi = (unsigned)(rec >> 32);
        int pos = atomicAdd(&cur[hi >> 16], 1);
        img[pos] = make_uint2(hi & 0xffffu, (unsigned)(rec & 0xffffffffu));
    }
    __syncthreads();
    for (int j = threadIdx.x; j < n; j += 512) csr8[p0 + j] = img[j];
}

// ---------------- build bf16 A level-0 slice [z|x|ph] at 0..160 + chunked mirror G0 ----------------
// G0 layout: [8 chunks][NN][20ch] -- per-XCD-resident gather source for pull #1.
__global__ void k_build_A(const float* __restrict__ z, const float* __restrict__ x,
                          const float* __restrict__ ph, u16* __restrict__ A,
                          u16* __restrict__ G0) {
    int i = blockIdx.x * 256 + threadIdx.x;
    if (i >= NN * 160) return;
    int n = i / 160, c = i - n * 160;
    float v;
    if (c < 64) v = z[n * 64 + c];
    else if (c < 96) v = x[n * 32 + (c - 64)];
    else v = ph[n * 64 + (c - 96)];
    u16 v16 = f2b(v);
    A[(size_t)n * 480 + c] = v16;
    int ck = c / 20, cl = c - ck * 20;
    G0[((size_t)ck * NN + n) * 20 + cl] = v16;
}

// ---------------- merged weight packing (Wp + W3p) ----------------
// A k-layout: [xin(0:96)|ph(96:160)|t1x(160:256)|t1h(256:320)|t2x(320:416)|t2h(416:480)]
__global__ void k_packW_all(const float* __restrict__ Wxz, const float* __restrict__ Wxr,
                            const float* __restrict__ Wxh, const float* __restrict__ Whz,
                            const float* __restrict__ Whr, const float* __restrict__ Whh,
                            u16* __restrict__ Wp, u16* __restrict__ W3p) {
    int idx = blockIdx.x * 256 + threadIdx.x;
    if (idx < 15 * 12 * 512) {
        int j = idx & 7, l = (idx >> 3) & 63;
        int ct = (idx >> 9) % 12, s = (idx >> 9) / 12;
        int k = 32 * s + (l >> 4) * 8 + j;
        int g = ct >> 2;
        int c = 16 * (ct & 3) + (l & 15);
        bool isX;
        int kr;
        if (k < 96)       { isX = true;  kr = k; }
        else if (k < 160) { isX = false; kr = k - 96; }
        else if (k < 256) { isX = true;  kr = 96 + (k - 160); }
        else if (k < 320) { isX = false; kr = 64 + (k - 256); }
        else if (k < 416) { isX = true;  kr = 192 + (k - 320); }
        else              { isX = false; kr = 128 + (k - 416); }
        float val;
        if (isX) {
            const float* W = (g == 0) ? Wxz : ((g == 1) ? Wxr : Wxh);
            val = W[kr * 64 + c];
        } else if (g == 2) {
            val = 0.f;
        } else {
            const float* W = (g == 0) ? Whz : Whr;
            val = W[kr * 64 + c];
        }
        Wp[idx] = f2b(val);
    } else {
        int i2 = idx - 15 * 12 * 512;
        if (i2 >= 6 * 4 * 512) return;
        int j = i2 & 7, l = (i2 >> 3) & 63;
        int ct = (i2 >> 9) & 3, s = i2 >> 11;
        int k = 32 * s + (l >> 4) * 8 + j;
        int ki = k >> 6, kr = k & 63;
        int c = 16 * ct + (l & 15);
        W3p[i2] = f2b(Whh[(ki * 64 + kr) * 64 + c]);
    }
}

// ---------------- chunked pull: channel-split across XCDs, L2-resident gathers ----------------
// chunk = blockIdx.x & 7 -> XCD affinity (round-robin dispatch). XCD c gathers only
// from Gin chunk c (NN*CPC*2B <= 2MB, L2-resident) -> random gathers become L2 hits;
// HBM traffic is streaming (csr + compulsory slice + writes) instead of 8x-replicated
// random slice reads (round-3..7: 137MB @ 2.9TB/s). Output dual-written: row-major
// (for MFMA consumers) + chunked Gout (gather source of next pull level), when needed.
template <int CPC, int TPR, int SCALE, bool HB, int OS, int BS>
__global__ __launch_bounds__(BS) void k_pull_c(
    const u16* __restrict__ Gin, const u16* __restrict__ Gbase,
    u16* __restrict__ Gout, u16* __restrict__ Arow, int outofs,
    const uint2* __restrict__ csr8, const int* __restrict__ row_ptr,
    const int* __restrict__ cnt) {
    constexpr int CW = CPC / TPR;   // channels per thread
    constexpr int RPB = BS / TPR;   // rows per block
    int c = blockIdx.x & 7;
    int team = threadIdx.x / TPR;
    int t = threadIdx.x - team * TPR;
    int r = (blockIdx.x >> 3) * RPB + team;
    if (r >= NN) return;
    const u16* gin = Gin + ((size_t)c * NN) * CPC + t * CW;
    int s0 = row_ptr[r], n = cnt[r];
    float acc[CW];
#pragma unroll
    for (int k = 0; k < CW; k++) acc[k] = 0.f;
    uint2 e = (n > 0) ? csr8[s0] : make_uint2(0u, 0u);
    for (int j = 0; j < n; j++) {
        uint2 ec = e;
        if (j + 1 < n) e = csr8[s0 + j + 1];
        float w = __uint_as_float(ec.y);
        const u16* sp = gin + (size_t)ec.x * CPC;
        if constexpr (CW == 8) {
            bf16x8 v = *(const bf16x8*)sp;
#pragma unroll
            for (int k = 0; k < 8; k++) acc[k] += w * b2f(v[k]);
        } else {
            bf16x4 v = *(const bf16x4*)sp;
#pragma unroll
            for (int k = 0; k < 4; k++) acc[k] += w * b2f(v[k]);
        }
    }
    const float sc = -(float)SCALE;
    float o[CW];
    if (HB) {
        const u16* bp = Gbase + ((size_t)c * NN + r) * CPC + t * CW;
        if constexpr (CW == 8) {
            bf16x8 b = *(const bf16x8*)bp;
#pragma unroll
            for (int k = 0; k < 8; k++) o[k] = sc * acc[k] - b2f(b[k]);
        } else {
            bf16x4 b = *(const bf16x4*)bp;
#pragma unroll
            for (int k = 0; k < 4; k++) o[k] = sc * acc[k] - b2f(b[k]);
        }
    } else {
#pragma unroll
        for (int k = 0; k < CW; k++) o[k] = sc * acc[k];
    }
    u16* arow = Arow + (size_t)r * OS + outofs + c * CPC + t * CW;
    if constexpr (CW == 8) {
        bf16x8 p;
#pragma unroll
        for (int k = 0; k < 8; k++) p[k] = (short)f2b(o[k]);
        *(bf16x8*)arow = p;
        if (Gout) *(bf16x8*)(Gout + ((size_t)c * NN + r) * CPC + t * CW) = p;
    } else {
        bf16x4 p;
#pragma unroll
        for (int k = 0; k < 4; k++) p[k] = (short)f2b(o[k]);
        *(bf16x4*)arow = p;
        if (Gout) *(bf16x4*)(Gout + ((size_t)c * NN + r) * CPC + t * CW) = p;
    }
}

// ---------------- gates GEMM (MFMA), gate-split: one wave = one gate x 16 rows ----------------
__global__ __launch_bounds__(256) void k_gates_mfma(
    const u16* __restrict__ A, const u16* __restrict__ Wp,
    const float* __restrict__ bxz, const float* __restrict__ bhz,
    const float* __restrict__ bxr, const float* __restrict__ bhr,
    const float* __restrict__ bxh,
    u16* __restrict__ Zb16, u16* __restrict__ Hx16, u16* __restrict__ A3,
    u16* __restrict__ G3) {
    int gw = (blockIdx.x * 256 + threadIdx.x) >> 6;
    int tile = gw / 3;
    int g = gw - tile * 3;
    int r0 = tile * 16;
    if (r0 >= NN) return;
    int lane = threadIdx.x & 63;
    int q = lane >> 4, j0 = lane & 15;

    f32x4 acc[4];
#pragma unroll
    for (int i = 0; i < 4; i++) acc[i] = (f32x4){0.f, 0.f, 0.f, 0.f};

    const u16* arow = A + (size_t)(r0 + j0) * 480 + q * 8;
    if (g < 2) {
        const u16* bp0 = Wp + (size_t)(g * 4) * 512 + lane * 8;
#pragma unroll
        for (int s = 0; s < 15; s++) {
            bf16x8 a = *(const bf16x8*)(arow + 32 * s);
            const u16* bp = bp0 + (size_t)(s * 12) * 512;
#pragma unroll
            for (int ct = 0; ct < 4; ct++) {
                bf16x8 b = *(const bf16x8*)(bp + ct * 512);
                acc[ct] = __builtin_amdgcn_mfma_f32_16x16x32_bf16(a, b, acc[ct], 0, 0, 0);
            }
        }
    } else {
        const int slist[9] = {0, 1, 2, 5, 6, 7, 10, 11, 12};
        const u16* bp0 = Wp + (size_t)8 * 512 + lane * 8;
#pragma unroll
        for (int si = 0; si < 9; si++) {
            int s = slist[si];
            bf16x8 a = *(const bf16x8*)(arow + 32 * s);
            const u16* bp = bp0 + (size_t)(s * 12) * 512;
#pragma unroll
            for (int ct = 0; ct < 4; ct++) {
                bf16x8 b = *(const bf16x8*)(bp + ct * 512);
                acc[ct] = __builtin_amdgcn_mfma_f32_16x16x32_bf16(a, b, acc[ct], 0, 0, 0);
            }
        }
    }

    if (g == 0) {
#pragma unroll
        for (int ct = 0; ct < 4; ct++) {
            int j = 16 * ct + j0;
            float bz = bxz[j] + bhz[j];
#pragma unroll
            for (int reg = 0; reg < 4; reg++) {
                int r = r0 + q * 4 + reg;
                float zv = 1.f / (1.f + expf(-(acc[ct][reg] + bz)));
                Zb16[(size_t)r * 64 + j] = f2b(zv);
            }
        }
    } else if (g == 1) {
#pragma unroll
        for (int ct = 0; ct < 4; ct++) {
            int j = 16 * ct + j0;
            float br = bxr[j] + bhr[j];
#pragma unroll
            for (int reg = 0; reg < 4; reg++) {
                int r = r0 + q * 4 + reg;
                float rv = 1.f / (1.f + expf(-(acc[ct][reg] + br)));
                float phv = b2f((short)A[(size_t)r * 480 + 96 + j]);
                u16 pv = f2b(rv * phv);
                A3[(size_t)r * 192 + j] = pv;
                G3[((size_t)(j >> 3) * NN + r) * 8 + (j & 7)] = pv;
            }
        }
    } else {
#pragma unroll
        for (int ct = 0; ct < 4; ct++) {
            int j = 16 * ct + j0;
            float bh = bxh[j];
#pragma unroll
            for (int reg = 0; reg < 4; reg++) {
                int r = r0 + q * 4 + reg;
                Hx16[(size_t)r * 64 + j] = f2b(acc[ct][reg] + bh);
            }
        }
    }
}

// ---------------- final GEMM (MFMA): [N,192]x[192,64] + GRU blend ----------------
__global__ __launch_bounds__(256) void k_final_mfma(
    const u16* __restrict__ A3, const u16* __restrict__ W3p,
    const float* __restrict__ bhh, const u16* __restrict__ Hx16,
    const u16* __restrict__ Zb16, const u16* __restrict__ A,
    float* __restrict__ outh) {
    int wv = (blockIdx.x * 256 + threadIdx.x) >> 6;
    int lane = threadIdx.x & 63;
    int r0 = wv * 16;
    if (r0 >= NN) return;
    int q = lane >> 4, j0 = lane & 15;

    f32x4 acc[4];
#pragma unroll
    for (int i = 0; i < 4; i++) acc[i] = (f32x4){0.f, 0.f, 0.f, 0.f};

    const u16* arow = A3 + (size_t)(r0 + j0) * 192 + q * 8;
#pragma unroll
    for (int s = 0; s < 6; s++) {
        bf16x8 a = *(const bf16x8*)(arow + 32 * s);
        const u16* bp = W3p + (size_t)(s * 4) * 512 + lane * 8;
#pragma unroll
        for (int ct = 0; ct < 4; ct++) {
            bf16x8 b = *(const bf16x8*)(bp + ct * 512);
            acc[ct] = __builtin_amdgcn_mfma_f32_16x16x32_bf16(a, b, acc[ct], 0, 0, 0);
        }
    }

#pragma unroll
    for (int ct = 0; ct < 4; ct++) {
        int j = 16 * ct + j0;
        float bh = bhh[j];
#pragma unroll
        for (int reg = 0; reg < 4; reg++) {
            int r = r0 + q * 4 + reg;
            size_t i = (size_t)r * 64 + j;
            float ht = tanhf(b2f((short)Hx16[i]) + acc[ct][reg] + bh);
            float zv = b2f((short)Zb16[i]);
            float phv = b2f((short)A[(size_t)r * 480 + 96 + j]);
            outh[i] = zv * phv + (1.f - zv) * ht;
        }
    }
}

// ---------------- tail: graph emb (binary search over sorted batch) + global emb ----------------
__global__ __launch_bounds__(256) void k_tail(
    const float* __restrict__ z, const int* __restrict__ batch,
    const float* __restrict__ u, const float* __restrict__ Wg,
    const float* __restrict__ bg, float* __restrict__ out) {
    int b = (blockIdx.x * 256 + threadIdx.x) >> 6;
    int lane = threadIdx.x & 63;
    if (b >= BB) return;
    int lo = 0, hi = NN;
    while (lo < hi) {
        int m = (lo + hi) >> 1;
        if (batch[m] < b) lo = m + 1; else hi = m;
    }
    int start = lo;
    hi = NN;
    while (lo < hi) {
        int m = (lo + hi) >> 1;
        if (batch[m] < b + 1) lo = m + 1; else hi = m;
    }
    int end = lo;
    float acc = 0.f;
    for (int n = start; n < end; n++) acc += z[(size_t)n * 64 + lane];
    float g = bg[lane];
    const float* ur = u + (size_t)b * 64;
    for (int k = 0; k < 64; k++) g += ur[k] * Wg[k * 64 + lane];
    g = fmaxf(g, 0.f);
    out[(size_t)b * 128 + lane] = acc;
    out[(size_t)b * 128 + 64 + lane] = g;
}

extern "C" void kernel_launch(void* const* d_in, const int* in_sizes, int n_in,
                              void* d_out, int out_size, void* d_ws, size_t ws_size,
                              hipStream_t stream) {
    const float* x  = (const float*)d_in[0];
    const float* u  = (const float*)d_in[1];
    const float* z  = (const float*)d_in[2];
    const int*   ei = (const int*)d_in[3];
    const float* ew = (const float*)d_in[4];
    const int* batch = (const int*)d_in[5];
    const float* ph = (const float*)d_in[7];
    const float *Wxz = (const float*)d_in[8],  *bxz = (const float*)d_in[9];
    const float *Whz = (const float*)d_in[10], *bhz = (const float*)d_in[11];
    const float *Wxr = (const float*)d_in[12], *bxr = (const float*)d_in[13];
    const float *Whr = (const float*)d_in[14], *bhr = (const float*)d_in[15];
    const float *Wxh = (const float*)d_in[16], *bxh = (const float*)d_in[17];
    const float *Whh = (const float*)d_in[18], *bhh = (const float*)d_in[19];
    const float *Wg  = (const float*)d_in[20], *bg  = (const float*)d_in[21];
    const int* src = ei;
    const int* dst = ei + EE;

    char* wsb = (char*)d_ws;
    size_t o = 0;
    auto alloc = [&](size_t bytes) {
        void* p = wsb + o;
        o += (bytes + 255) & ~(size_t)255;
        return p;
    };
    float* deg_p   = (float*)alloc((size_t)NC * NN * 4);  // 6.4MB, dead after scan3/bin
    int*   cnt_p   = (int*)alloc((size_t)NC * NN * 4);    // 6.4MB, dead after scan1
    int*   cnt     = (int*)alloc(NN * 4);
    int*   incl    = (int*)alloc(NN * 4);
    int*   row_ptr = (int*)alloc(NN * 4);
    float* dinv    = (float*)alloc(NN * 4);
    int*   bsum    = (int*)alloc(256 * 4);
    int*   scur    = (int*)alloc(NRB * 4);
    uint2* csr8    = (uint2*)alloc((size_t)EE * 8);
    u16*   Zb16 = (u16*)alloc((size_t)NN * 64 * 2);
    u16*   Hx16 = (u16*)alloc((size_t)NN * 64 * 2);
    u16*   A    = (u16*)alloc((size_t)NN * 480 * 2);
    u16*   A3   = (u16*)alloc((size_t)NN * 192 * 2);
    u16*   Wp   = (u16*)alloc(15 * 12 * 512 * 2);
    u16*   W3p  = (u16*)alloc(6 * 4 * 512 * 2);
    u16*   G0   = (u16*)alloc((size_t)NN * 160 * 2);  // chunked [8][NN][20], gather src L0
    u16*   G1   = (u16*)alloc((size_t)NN * 160 * 2);  // chunked t1
    // aliases (all uses strictly after k_sortrange):
    u64*   stage = (u64*)deg_p;   // 6.4MB, bin->sortrange
    u16*   G3    = (u16*)deg_p;   // 6.4MB chunked [8][NN][8], written by gates
    u16*   G4    = (u16*)cnt_p;   // 6.4MB chunked t1h, written by pull64 #1

    float* outF = (float*)d_out;               // [B,128]
    float* outH = outF + (size_t)BB * 128;     // [N,64]

    const int BLK = 256;
    const int gA = (NN * 160 + BLK - 1) / BLK;
    const int gPc160 = 8 * ((NN + 63) / 64);    // 8 chunks x 782 row-blocks, 320 thr (64 rows x 5)
    const int gPc64  = 8 * ((NN + 255) / 256);  // 8 chunks x 196 row-blocks, 256 thr (256 rows x 1)
    const int gGates = (3 * 3125 + 3) / 4;
    const int gMFMA = (3125 + 3) / 4;
    const int gPack = (15 * 12 * 512 + 6 * 4 * 512 + BLK - 1) / BLK;

    // 0. independent prep
    k_packW_all<<<gPack, BLK, 0, stream>>>(Wxz, Wxr, Wxh, Whz, Whr, Whh, Wp, W3p);
    k_build_A<<<gA, BLK, 0, stream>>>(z, x, ph, A, G0);

    // 1. degree + indegree
    k_degcnt_lds<<<NR * NC, 512, 0, stream>>>(src, dst, ew, deg_p, cnt_p);

    // 2. CSR scan
    k_scan1<<<NB, 256, 0, stream>>>(cnt_p, cnt, incl, bsum);
    k_scan2<<<1, 256, 0, stream>>>(bsum);
    k_scan3<<<NB, 256, 0, stream>>>(incl, cnt, bsum, row_ptr, scur, deg_p, dinv);

    // 2b. two-pass CSR build
    k_bin<<<NBIN, 512, 0, stream>>>(src, dst, ew, dinv, scur, stage);
    k_sortrange<<<NRB, 512, 0, stream>>>(stage, row_ptr, csr8);

    // 3. Chebyshev bases, channel-chunked pulls: t1 = -prop(t0); t2 = -2*prop(t1) - t0
    k_pull_c<20, 5, 1, false, 480, 320><<<gPc160, 320, 0, stream>>>(
        G0, nullptr, G1, A, 160, csr8, row_ptr, cnt);
    k_pull_c<20, 5, 2, true, 480, 320><<<gPc160, 320, 0, stream>>>(
        G1, G0, nullptr, A, 320, csr8, row_ptr, cnt);

    // 4. gates GEMM (gate-split) -> Zb16, Hx16, A3 slice 0 + chunked G3
    k_gates_mfma<<<gGates, BLK, 0, stream>>>(A, Wp, bxz, bhz, bxr, bhr, bxh,
                                             Zb16, Hx16, A3, G3);

    // 5. Chebyshev basis for hr (chunked)
    k_pull_c<8, 1, 1, false, 192, 256><<<gPc64, 256, 0, stream>>>(
        G3, nullptr, G4, A3, 64, csr8, row_ptr, cnt);
    k_pull_c<8, 1, 2, true, 192, 256><<<gPc64, 256, 0, stream>>>(
        G4, G3, nullptr, A3, 128, csr8, row_ptr, cnt);

    // 6. candidate GEMM + GRU blend -> h out
    k_final_mfma<<<gMFMA, BLK, 0, stream>>>(A3, W3p, bhh, Hx16, Zb16, A, outH);

    // 7. tail
    k_tail<<<(BB * 64 + BLK - 1) / BLK, BLK, 0, stream>>>(z, batch, u, Wg, bg, outF);
}

// Round 9
// 406.945 us; speedup vs baseline: 1.4671x; 1.4671x over previous
//
#include <hip/hip_runtime.h>

#define NN 50000
#define EE 800000
#define BB 1000
#define NB 196  // ceil(NN/256)
#define NR 8        // node ranges for LDS histogram
#define RS 6272     // range size, NR*RS = 50176 >= NN
#define NC 32       // edge chunks / partial copies
#define CHUNK 25000 // EE/NC

// two-pass scatter: 160 dst ranges of 314 rows; bin -> in-LDS sort
#define NRB 160
#define RSB 314     // 160*314 = 50240 >= NN
#define NBIN 256    // bin blocks
#define CH2 3125    // EE/NBIN
#define CAP 7000    // per-range LDS image capacity (mean 5024, +28 sigma)

typedef unsigned short u16;
typedef unsigned long long u64;
typedef __attribute__((ext_vector_type(8))) short bf16x8;
typedef __attribute__((ext_vector_type(4))) float f32x4;

static __device__ __forceinline__ u16 f2b(float f) {
    union { float f; unsigned u; } v;
    v.f = f;
    unsigned r = v.u + 0x7fffu + ((v.u >> 16) & 1u);
    return (u16)(r >> 16);
}

static __device__ __forceinline__ float b2f(short s) {
    union { unsigned u; float f; } c;
    c.u = ((unsigned)(u16)s) << 16;
    return c.f;
}

// ---------------- degree(src)+indegree(dst): LDS-privatized, zero global atomics ----------------
// block (r = bid&7, c = bid>>3): range r of nodes, chunk c of edges.
__global__ __launch_bounds__(512) void k_degcnt_lds(
    const int* __restrict__ src, const int* __restrict__ dst,
    const float* __restrict__ ew, float* __restrict__ deg_p,
    int* __restrict__ cnt_p) {
    __shared__ float sdeg[RS];
    __shared__ int scnt[RS];
    int r = blockIdx.x & (NR - 1);
    int c = blockIdx.x >> 3;
    int base = r * RS;
    for (int i = threadIdx.x; i < RS; i += 512) {
        sdeg[i] = 0.f;
        scnt[i] = 0;
    }
    __syncthreads();
    int e0 = c * CHUNK;
    for (int j = threadIdx.x; j < CHUNK; j += 512) {
        int e = e0 + j;
        int s = src[e], d = dst[e];
        int sl = s - base, dl = d - base;
        if ((unsigned)sl < RS) atomicAdd(&sdeg[sl], ew[e]);
        if ((unsigned)dl < RS) atomicAdd(&scnt[dl], 1);
    }
    __syncthreads();
    int lim = (NN - base < RS) ? (NN - base) : RS;
    for (int i = threadIdx.x; i < lim; i += 512) {
        deg_p[(size_t)c * NN + base + i] = sdeg[i];
        cnt_p[(size_t)c * NN + base + i] = scnt[i];
    }
}

// ---------------- CSR scan (scan1 reduces cnt copies) ----------------
__global__ void k_scan1(const int* __restrict__ cnt_p, int* __restrict__ cnt,
                        int* __restrict__ incl, int* __restrict__ bsum) {
    __shared__ int s[256];
    int i = blockIdx.x * 256 + threadIdx.x;
    int v = 0;
    if (i < NN) {
#pragma unroll
        for (int p = 0; p < NC; p++) v += cnt_p[(size_t)p * NN + i];
        cnt[i] = v;
    }
    s[threadIdx.x] = v;
    __syncthreads();
    for (int off = 1; off < 256; off <<= 1) {
        int t = (threadIdx.x >= off) ? s[threadIdx.x - off] : 0;
        __syncthreads();
        s[threadIdx.x] += t;
        __syncthreads();
    }
    if (i < NN) incl[i] = s[threadIdx.x];
    if (threadIdx.x == 255) bsum[blockIdx.x] = s[255];
}

__global__ void k_scan2(int* __restrict__ bsum) {
    __shared__ int s[256];
    int v = (threadIdx.x < NB) ? bsum[threadIdx.x] : 0;
    s[threadIdx.x] = v;
    __syncthreads();
    for (int off = 1; off < 256; off <<= 1) {
        int t = (threadIdx.x >= off) ? s[threadIdx.x - off] : 0;
        __syncthreads();
        s[threadIdx.x] += t;
        __syncthreads();
    }
    if (threadIdx.x < NB) bsum[threadIdx.x] = s[threadIdx.x];
}

// scan3: row_ptr + range stage cursors + dinv (reduces deg copies)
__global__ void k_scan3(const int* __restrict__ incl, const int* __restrict__ cnt,
                        const int* __restrict__ bsum, int* __restrict__ row_ptr,
                        int* __restrict__ scur, const float* __restrict__ deg_p,
                        float* __restrict__ dinv) {
    int i = blockIdx.x * 256 + threadIdx.x;
    if (i >= NN) return;
    int off = (blockIdx.x > 0) ? bsum[blockIdx.x - 1] : 0;
    int start = off + incl[i] - cnt[i];
    row_ptr[i] = start;
    if (i % RSB == 0) scur[i / RSB] = start;  // stage cursor = range extent start
    float d = 0.f;
#pragma unroll
    for (int p = 0; p < NC; p++) d += deg_p[(size_t)p * NN + i];
    dinv[i] = d > 0.f ? rsqrtf(d) : 0.f;
}

// ---------------- pass B: bin edges by dst range, append packed records ----------------
// Record: hi32 = (dlocal<<16)|src  (dlocal<314 fits 9b, src<50000 fits 16b), lo32 = w.
// Per-(block,range) appends are contiguous runs (~20 recs) -> coalesced writes,
// one global atomic per (block,range) instead of one per edge.
__global__ __launch_bounds__(512) void k_bin(
    const int* __restrict__ src, const int* __restrict__ dst,
    const float* __restrict__ ew, const float* __restrict__ dinv,
    int* __restrict__ scur, u64* __restrict__ stage) {
    __shared__ int cntA[NRB], baseB[NRB], rk[NRB];
    int e0 = blockIdx.x * CH2;
    for (int i = threadIdx.x; i < NRB; i += 512) cntA[i] = 0;
    __syncthreads();
    for (int j = threadIdx.x; j < CH2; j += 512) {
        int d = dst[e0 + j];
        atomicAdd(&cntA[d / RSB], 1);
    }
    __syncthreads();
    for (int i = threadIdx.x; i < NRB; i += 512) {
        baseB[i] = atomicAdd(&scur[i], cntA[i]);
        rk[i] = 0;
    }
    __syncthreads();
    for (int j = threadIdx.x; j < CH2; j += 512) {
        int e = e0 + j;
        int d = dst[e], s = src[e];
        int r = d / RSB;
        int slot = baseB[r] + atomicAdd(&rk[r], 1);
        float w = dinv[s] * ew[e] * dinv[d];
        unsigned dl = (unsigned)(d - r * RSB);
        u64 rec = ((u64)((dl << 16) | (unsigned)s) << 32) | (u64)__float_as_uint(w);
        stage[slot] = rec;
    }
}

// ---------------- pass C: per-range in-LDS counting sort -> coalesced CSR write ----------------
__global__ __launch_bounds__(512) void k_sortrange(
    const u64* __restrict__ stage, const int* __restrict__ row_ptr,
    uint2* __restrict__ csr8) {
    __shared__ uint2 img[CAP];
    __shared__ int cur[RSB];
    int r = blockIdx.x;
    int r0 = r * RSB;
    int nrows = (NN - r0 < RSB) ? (NN - r0) : RSB;
    int p0 = row_ptr[r0];
    int p1 = (r0 + nrows < NN) ? row_ptr[r0 + nrows] : EE;
    for (int i = threadIdx.x; i < nrows; i += 512) cur[i] = row_ptr[r0 + i] - p0;
    __syncthreads();
    int n = p1 - p0;
    for (int j = threadIdx.x; j < n; j += 512) {
        u64 rec = stage[p0 + j];
        unsigned hi = (unsigned)(rec >> 32);
        int pos = atomicAdd(&cur[hi >> 16], 1);
        img[pos] = make_uint2(hi & 0xffffu, (unsigned)(rec & 0xffffffffu));
    }
    __syncthreads();
    for (int j = threadIdx.x; j < n; j += 512) csr8[p0 + j] = img[j];
}

// ---------------- build bf16 A level-0 slice: [z | x | ph] at 0..160 ----------------
__global__ void k_build_A(const float* __restrict__ z, const float* __restrict__ x,
                          const float* __restrict__ ph, u16* __restrict__ A) {
    int i = blockIdx.x * 256 + threadIdx.x;
    if (i >= NN * 160) return;
    int n = i / 160, c = i - n * 160;
    float v;
    if (c < 64) v = z[n * 64 + c];
    else if (c < 96) v = x[n * 32 + (c - 64)];
    else v = ph[n * 64 + (c - 96)];
    A[(size_t)n * 480 + c] = f2b(v);
}

// ---------------- merged weight packing (Wp + W3p) ----------------
// A k-layout: [xin(0:96)|ph(96:160)|t1x(160:256)|t1h(256:320)|t2x(320:416)|t2h(416:480)]
__global__ void k_packW_all(const float* __restrict__ Wxz, const float* __restrict__ Wxr,
                            const float* __restrict__ Wxh, const float* __restrict__ Whz,
                            const float* __restrict__ Whr, const float* __restrict__ Whh,
                            u16* __restrict__ Wp, u16* __restrict__ W3p) {
    int idx = blockIdx.x * 256 + threadIdx.x;
    if (idx < 15 * 12 * 512) {
        int j = idx & 7, l = (idx >> 3) & 63;
        int ct = (idx >> 9) % 12, s = (idx >> 9) / 12;
        int k = 32 * s + (l >> 4) * 8 + j;
        int g = ct >> 2;
        int c = 16 * (ct & 3) + (l & 15);
        bool isX;
        int kr;
        if (k < 96)       { isX = true;  kr = k; }
        else if (k < 160) { isX = false; kr = k - 96; }
        else if (k < 256) { isX = true;  kr = 96 + (k - 160); }
        else if (k < 320) { isX = false; kr = 64 + (k - 256); }
        else if (k < 416) { isX = true;  kr = 192 + (k - 320); }
        else              { isX = false; kr = 128 + (k - 416); }
        float val;
        if (isX) {
            const float* W = (g == 0) ? Wxz : ((g == 1) ? Wxr : Wxh);
            val = W[kr * 64 + c];
        } else if (g == 2) {
            val = 0.f;
        } else {
            const float* W = (g == 0) ? Whz : Whr;
            val = W[kr * 64 + c];
        }
        Wp[idx] = f2b(val);
    } else {
        int i2 = idx - 15 * 12 * 512;
        if (i2 >= 6 * 4 * 512) return;
        int j = i2 & 7, l = (i2 >> 3) & 63;
        int ct = (i2 >> 9) & 3, s = i2 >> 11;
        int k = 32 * s + (l >> 4) * 8 + j;
        int ki = k >> 6, kr = k & 63;
        int c = 16 * ct + (l & 15);
        W3p[i2] = f2b(Whh[(ki * 64 + kr) * 64 + c]);
    }
}

// ---------------- bf16 pull propagation ----------------
template <int C, int SCALE, bool HB, int BS, int OS>
__global__ __launch_bounds__(BS) void k_pull(
    const u16* __restrict__ Abase, int inofs, int baseofs, int outofs,
    const uint2* __restrict__ csr8, const int* __restrict__ row_ptr,
    const int* __restrict__ cnt) {
    constexpr int TPR = C / 8;
    int tid = blockIdx.x * BS + threadIdx.x;
    int r = tid / TPR;
    int c8 = (tid - r * TPR) * 8;
    if (r >= NN) return;
    int s0 = row_ptr[r], n = cnt[r];
    float acc[8] = {0.f, 0.f, 0.f, 0.f, 0.f, 0.f, 0.f, 0.f};
    const u16* in = Abase + inofs + c8;
    uint2 e = (n > 0) ? csr8[s0] : make_uint2(0u, 0u);
    for (int j = 0; j < n; j++) {
        uint2 ec = e;
        if (j + 1 < n) e = csr8[s0 + j + 1];
        float w = __uint_as_float(ec.y);
        bf16x8 v = *(const bf16x8*)(in + (size_t)ec.x * OS);
#pragma unroll
        for (int k = 0; k < 8; k++) acc[k] += w * b2f(v[k]);
    }
    const float sc = -(float)SCALE;
    float o[8];
    if (HB) {
        bf16x8 b = *(const bf16x8*)(Abase + (size_t)r * OS + baseofs + c8);
#pragma unroll
        for (int k = 0; k < 8; k++) o[k] = sc * acc[k] - b2f(b[k]);
    } else {
#pragma unroll
        for (int k = 0; k < 8; k++) o[k] = sc * acc[k];
    }
    bf16x8 p;
#pragma unroll
    for (int k = 0; k < 8; k++) p[k] = (short)f2b(o[k]);
    *(bf16x8*)(const_cast<u16*>(Abase) + (size_t)r * OS + outofs + c8) = p;
}

// ---------------- gates GEMM (MFMA): [N,480]x[480,192] -> Zb16, Hx16, A3 slice ----------------
__global__ __launch_bounds__(256) void k_gates_mfma(
    const u16* __restrict__ A, const u16* __restrict__ Wp,
    const float* __restrict__ bxz, const float* __restrict__ bhz,
    const float* __restrict__ bxr, const float* __restrict__ bhr,
    const float* __restrict__ bxh,
    u16* __restrict__ Zb16, u16* __restrict__ Hx16, u16* __restrict__ A3) {
    int wv = (blockIdx.x * 256 + threadIdx.x) >> 6;
    int lane = threadIdx.x & 63;
    int r0 = wv * 16;
    if (r0 >= NN) return;
    int q = lane >> 4, j0 = lane & 15;

    f32x4 acc[12];
#pragma unroll
    for (int i = 0; i < 12; i++) acc[i] = (f32x4){0.f, 0.f, 0.f, 0.f};

    const u16* arow = A + (size_t)(r0 + j0) * 480 + q * 8;
#pragma unroll
    for (int s = 0; s < 15; s++) {
        bf16x8 a = *(const bf16x8*)(arow + 32 * s);
        const u16* bp = Wp + (size_t)(s * 12) * 512 + lane * 8;
#pragma unroll
        for (int ct = 0; ct < 12; ct++) {
            bf16x8 b = *(const bf16x8*)(bp + ct * 512);
            acc[ct] = __builtin_amdgcn_mfma_f32_16x16x32_bf16(a, b, acc[ct], 0, 0, 0);
        }
    }

#pragma unroll
    for (int ct = 0; ct < 4; ct++) {
        int j = 16 * ct + j0;
        float bz = bxz[j] + bhz[j];
        float br = bxr[j] + bhr[j];
        float bh = bxh[j];
#pragma unroll
        for (int reg = 0; reg < 4; reg++) {
            int r = r0 + q * 4 + reg;
            size_t i = (size_t)r * 64 + j;
            float zp = acc[ct][reg] + bz;
            float rp = acc[ct + 4][reg] + br;
            float hp = acc[ct + 8][reg] + bh;
            float zv = 1.f / (1.f + expf(-zp));
            float rv = 1.f / (1.f + expf(-rp));
            float phv = b2f((short)A[(size_t)r * 480 + 96 + j]);
            Zb16[i] = f2b(zv);
            Hx16[i] = f2b(hp);
            A3[(size_t)r * 192 + j] = f2b(rv * phv);
        }
    }
}

// ---------------- final GEMM (MFMA): [N,192]x[192,64] + GRU blend ----------------
__global__ __launch_bounds__(256) void k_final_mfma(
    const u16* __restrict__ A3, const u16* __restrict__ W3p,
    const float* __restrict__ bhh, const u16* __restrict__ Hx16,
    const u16* __restrict__ Zb16, const u16* __restrict__ A,
    float* __restrict__ outh) {
    int wv = (blockIdx.x * 256 + threadIdx.x) >> 6;
    int lane = threadIdx.x & 63;
    int r0 = wv * 16;
    if (r0 >= NN) return;
    int q = lane >> 4, j0 = lane & 15;

    f32x4 acc[4];
#pragma unroll
    for (int i = 0; i < 4; i++) acc[i] = (f32x4){0.f, 0.f, 0.f, 0.f};

    const u16* arow = A3 + (size_t)(r0 + j0) * 192 + q * 8;
#pragma unroll
    for (int s = 0; s < 6; s++) {
        bf16x8 a = *(const bf16x8*)(arow + 32 * s);
        const u16* bp = W3p + (size_t)(s * 4) * 512 + lane * 8;
#pragma unroll
        for (int ct = 0; ct < 4; ct++) {
            bf16x8 b = *(const bf16x8*)(bp + ct * 512);
            acc[ct] = __builtin_amdgcn_mfma_f32_16x16x32_bf16(a, b, acc[ct], 0, 0, 0);
        }
    }

#pragma unroll
    for (int ct = 0; ct < 4; ct++) {
        int j = 16 * ct + j0;
        float bh = bhh[j];
#pragma unroll
        for (int reg = 0; reg < 4; reg++) {
            int r = r0 + q * 4 + reg;
            size_t i = (size_t)r * 64 + j;
            float ht = tanhf(b2f((short)Hx16[i]) + acc[ct][reg] + bh);
            float zv = b2f((short)Zb16[i]);
            float phv = b2f((short)A[(size_t)r * 480 + 96 + j]);
            outh[i] = zv * phv + (1.f - zv) * ht;
        }
    }
}

// ---------------- tail: graph emb (binary search over sorted batch) + global emb ----------------
__global__ __launch_bounds__(256) void k_tail(
    const float* __restrict__ z, const int* __restrict__ batch,
    const float* __restrict__ u, const float* __restrict__ Wg,
    const float* __restrict__ bg, float* __restrict__ out) {
    int b = (blockIdx.x * 256 + threadIdx.x) >> 6;
    int lane = threadIdx.x & 63;
    if (b >= BB) return;
    // lower_bound(batch, b) and lower_bound(batch, b+1)
    int lo = 0, hi = NN;
    while (lo < hi) {
        int m = (lo + hi) >> 1;
        if (batch[m] < b) lo = m + 1; else hi = m;
    }
    int start = lo;
    hi = NN;
    while (lo < hi) {
        int m = (lo + hi) >> 1;
        if (batch[m] < b + 1) lo = m + 1; else hi = m;
    }
    int end = lo;
    float acc = 0.f;
    for (int n = start; n < end; n++) acc += z[(size_t)n * 64 + lane];
    float g = bg[lane];
    const float* ur = u + (size_t)b * 64;
    for (int k = 0; k < 64; k++) g += ur[k] * Wg[k * 64 + lane];
    g = fmaxf(g, 0.f);
    out[(size_t)b * 128 + lane] = acc;
    out[(size_t)b * 128 + 64 + lane] = g;
}

extern "C" void kernel_launch(void* const* d_in, const int* in_sizes, int n_in,
                              void* d_out, int out_size, void* d_ws, size_t ws_size,
                              hipStream_t stream) {
    const float* x  = (const float*)d_in[0];
    const float* u  = (const float*)d_in[1];
    const float* z  = (const float*)d_in[2];
    const int*   ei = (const int*)d_in[3];
    const float* ew = (const float*)d_in[4];
    const int* batch = (const int*)d_in[5];
    const float* ph = (const float*)d_in[7];
    const float *Wxz = (const float*)d_in[8],  *bxz = (const float*)d_in[9];
    const float *Whz = (const float*)d_in[10], *bhz = (const float*)d_in[11];
    const float *Wxr = (const float*)d_in[12], *bxr = (const float*)d_in[13];
    const float *Whr = (const float*)d_in[14], *bhr = (const float*)d_in[15];
    const float *Wxh = (const float*)d_in[16], *bxh = (const float*)d_in[17];
    const float *Whh = (const float*)d_in[18], *bhh = (const float*)d_in[19];
    const float *Wg  = (const float*)d_in[20], *bg  = (const float*)d_in[21];
    const int* src = ei;
    const int* dst = ei + EE;

    char* wsb = (char*)d_ws;
    size_t o = 0;
    auto alloc = [&](size_t bytes) {
        void* p = wsb + o;
        o += (bytes + 255) & ~(size_t)255;
        return p;
    };
    float* deg_p   = (float*)alloc((size_t)NC * NN * 4);  // fully overwritten, no memset
    int*   cnt_p   = (int*)alloc((size_t)NC * NN * 4);    // fully overwritten, no memset
    int*   cnt     = (int*)alloc(NN * 4);
    int*   incl    = (int*)alloc(NN * 4);
    int*   row_ptr = (int*)alloc(NN * 4);
    float* dinv    = (float*)alloc(NN * 4);
    int*   bsum    = (int*)alloc(256 * 4);
    int*   scur    = (int*)alloc(NRB * 4);
    uint2* csr8    = (uint2*)alloc((size_t)EE * 8);
    u16*   Zb16 = (u16*)alloc((size_t)NN * 64 * 2);
    u16*   Hx16 = (u16*)alloc((size_t)NN * 64 * 2);
    u16*   A    = (u16*)alloc((size_t)NN * 480 * 2);
    u16*   A3   = (u16*)alloc((size_t)NN * 192 * 2);
    u16*   Wp   = (u16*)alloc(15 * 12 * 512 * 2);
    u16*   W3p  = (u16*)alloc(6 * 4 * 512 * 2);
    // stage aliases deg_p: deg_p (NC*NN*4 = 6.4MB) is dead after k_scan3,
    // stage (EE*8 = 6.4MB) is written in k_bin (after scan3) -> safe reuse.
    u64*   stage = (u64*)deg_p;

    float* outF = (float*)d_out;               // [B,128]
    float* outH = outF + (size_t)BB * 128;     // [N,64]

    const int BLK = 256;
    const int gA = (NN * 160 + BLK - 1) / BLK;
    const int gPull160 = (NN + 15) / 16;  // 320 thr, 20 thr/row -> 16 rows/blk
    const int gPull64 = (NN + 31) / 32;   // 256 thr, 8 thr/row -> 32 rows/blk
    const int gMFMA = (3125 + 3) / 4;
    const int gPack = (15 * 12 * 512 + 6 * 4 * 512 + BLK - 1) / BLK;

    // 0. independent prep
    k_packW_all<<<gPack, BLK, 0, stream>>>(Wxz, Wxr, Wxh, Whz, Whr, Whh, Wp, W3p);
    k_build_A<<<gA, BLK, 0, stream>>>(z, x, ph, A);

    // 1. degree + indegree: LDS histograms, no global atomics, no memset
    k_degcnt_lds<<<NR * NC, 512, 0, stream>>>(src, dst, ew, deg_p, cnt_p);

    // 2. CSR scan (dinv + stage cursors in scan3)
    k_scan1<<<NB, 256, 0, stream>>>(cnt_p, cnt, incl, bsum);
    k_scan2<<<1, 256, 0, stream>>>(bsum);
    k_scan3<<<NB, 256, 0, stream>>>(incl, cnt, bsum, row_ptr, scur, deg_p, dinv);

    // 2b. two-pass CSR build: bin (coalesced appends) + per-range LDS sort
    k_bin<<<NBIN, 512, 0, stream>>>(src, dst, ew, dinv, scur, stage);
    k_sortrange<<<NRB, 512, 0, stream>>>(stage, row_ptr, csr8);

    // 3. Chebyshev bases, merged 160-ch pulls: t1 = -prop(t0); t2 = -2*prop(t1) - t0
    k_pull<160, 1, false, 320, 480><<<gPull160, 320, 0, stream>>>(A, 0, 0, 160, csr8, row_ptr, cnt);
    k_pull<160, 2, true, 320, 480><<<gPull160, 320, 0, stream>>>(A, 160, 0, 320, csr8, row_ptr, cnt);

    // 4. gates GEMM -> Zb16, Hx16, A3 slice 0 (hr)
    k_gates_mfma<<<gMFMA, BLK, 0, stream>>>(A, Wp, bxz, bhz, bxr, bhr, bxh, Zb16, Hx16, A3);

    // 5. Chebyshev basis for hr (in A3)
    k_pull<64, 1, false, 256, 192><<<gPull64, 256, 0, stream>>>(A3, 0, 0, 64, csr8, row_ptr, cnt);
    k_pull<64, 2, true, 256, 192><<<gPull64, 256, 0, stream>>>(A3, 64, 0, 128, csr8, row_ptr, cnt);

    // 6. candidate GEMM + GRU blend -> h out
    k_final_mfma<<<gMFMA, BLK, 0, stream>>>(A3, W3p, bhh, Hx16, Zb16, A, outH);

    // 7. tail: graph emb (binary search) + global emb -> fused out
    k_tail<<<(BB * 64 + BLK - 1) / BLK, BLK, 0, stream>>>(z, batch, u, Wg, bg, outF);
}